// Round 6
// baseline (342.365 us; speedup 1.0000x reference)
//
#include <hip/hip_runtime.h>
#include <math.h>

#define TOKENS    1024
#define IN_W      512
#define BLOCK_H   256
#define OUT_W     512
#define N_EXPERTS 64
#define TOPK      2
#define NSLOTS    (TOKENS * TOPK)
#define LIST_CAP  128     // ne ~ Binom(2048,1/64): mean 32, sigma 5.6; 128 is +17 sigma
#define T_CAP     12      // tokens per pass; ne <= 48 in one pass (99.8%)
#define NGRP      4       // groups per expert -> grid 256 = 1 block/CU

// ---------------------------------------------------------------------------
// Routing + fused compaction (verified; also zeroes `out`).
// ---------------------------------------------------------------------------
__global__ __launch_bounds__(256) void routing_kernel(
    const float* __restrict__ x, const float* __restrict__ noise,
    const float* __restrict__ mixer, const float* __restrict__ noisec,
    float* __restrict__ esc, int* __restrict__ counts, int* __restrict__ lists,
    float* __restrict__ out)
{
    __shared__ float xs[2 * 512];
    __shared__ float pm[2 * 2 * 64];
    __shared__ float pn[2 * 2 * 64];
    const int blk  = blockIdx.x;
    const int tid  = threadIdx.x;
    const int wave = tid >> 6, lane = tid & 63;
    const int tq = wave >> 1;
    const int ih = wave & 1;

    ((float4*)xs)[tid] = ((const float4*)x)[(size_t)blk * 256 + tid];
    ((float4*)(out + (size_t)blk * 2 * OUT_W))[tid] = make_float4(0.f, 0.f, 0.f, 0.f);
    __syncthreads();

    float am = 0.f, an = 0.f;
    const float* xp = xs + tq * 512 + ih * 256;
    const float* mp = mixer  + (size_t)(ih * 256) * 64 + lane;
    const float* np = noisec + (size_t)(ih * 256) * 64 + lane;
    #pragma unroll 8
    for (int i = 0; i < 256; ++i) {
        const float xv = xp[i];
        am = fmaf(xv, mp[i * 64], am);
        an = fmaf(xv, np[i * 64], an);
    }
    pm[tq * 128 + ih * 64 + lane] = am;
    pn[tq * 128 + ih * 64 + lane] = an;
    __syncthreads();

    if (tid < 128) {
        const int e = tid & 63, tt = tid >> 6;
        const int t = blk * 2 + tt;
        const float am2 = pm[tt * 128 + e] + pm[tt * 128 + 64 + e];
        const float an2 = pn[tt * 128 + e] + pn[tt * 128 + 64 + e];
        const float sp = fmaxf(an2, 0.f) + log1pf(expf(-fabsf(an2)));
        pm[tt * 128 + e] = am2 + noise[(size_t)t * 64 + e] * sp;
    }
    __syncthreads();

    if (tid < 2) {
        const float* h = pm + tid * 128;
        float b0 = -INFINITY, b1 = -INFINITY;
        int i0 = 0, i1 = 0;
        for (int i = 0; i < N_EXPERTS; ++i) {
            const float v = h[i];
            if (v > b0)      { b1 = b0; i1 = i0; b0 = v; i0 = i; }
            else if (v > b1) { b1 = v; i1 = i; }
        }
        const float z   = expf(b1 - b0);
        const float inv = 1.f / (1.f + z);
        const int t = blk * 2 + tid;
        esc[t * 2 + 0] = inv;
        esc[t * 2 + 1] = z * inv;
        const int p0 = atomicAdd(&counts[i0], 1);
        if (p0 < LIST_CAP) lists[i0 * LIST_CAP + p0] = t * 2 + 0;
        const int p1 = atomicAdd(&counts[i1], 1);
        if (p1 < LIST_CAP) lists[i1 * LIST_CAP + p1] = t * 2 + 1;
    }
}

// ---------------------------------------------------------------------------
// Fused expert FFN, v8: weight-STATIONARY slices. W1 in 8 slices [512][32]
// (64 KB, single-buffered; 4 DMA/thread -> 64 KB in flight, transfer-bound),
// W2 in 16 slices [256][32] (32 KB, double-buffered in the same 64 KB; next
// slice's DMA issued before current compute so the barrier drain overlaps).
// Wave roles: f4-col slot = wave&7 (slice has 8 f4-cols), token-group =
// wave>>3 (2 x 6 tokens of T_CAP=12); lane = row mod 64; acc[6] (24 VGPR).
// Bank math at 16B-position granularity: weights swizzled c4^(row&7) across
// the full 128B line (8 positions x 8 lanes = b128 minimum); x and v stored
// transposed lane-major in 4-float units (position = lane&7, conflict-free).
// ---------------------------------------------------------------------------
__device__ __forceinline__ void red_xor(float4& v, int m) {
    v.x += __shfl_xor(v.x, m); v.y += __shfl_xor(v.y, m);
    v.z += __shfl_xor(v.z, m); v.w += __shfl_xor(v.w, m);
}

__device__ __forceinline__ void fma4(float4& a, float s, const float4& w) {
    a.x = fmaf(s, w.x, a.x); a.y = fmaf(s, w.y, a.y);
    a.z = fmaf(s, w.z, a.z); a.w = fmaf(s, w.w, a.w);
}

__device__ __forceinline__ float comp(const float4& v, int k) {  // k literal under unroll
    return k == 0 ? v.x : k == 1 ? v.y : k == 2 ? v.z : v.w;
}

// W1 slice p: [512 rows][8 f4-cols] = 64 KB. Storage slot c4s holds logical
// col c4s^(r&7); global source pre-applies the involution.
__device__ __forceinline__ void stage_w1(const char* w1e, float* Wl, int p, int tid) {
    #pragma unroll
    for (int j = 0; j < 4; ++j) {
        const int o  = (j * 1024 + tid) * 16;          // byte in 64 KB image
        const int r  = o >> 7;                          // row (128 B rows)
        const int c4 = ((o >> 4) & 7) ^ (r & 7);        // logical f4-col
        __builtin_amdgcn_global_load_lds(
            (const __attribute__((address_space(1))) void*)(w1e + (size_t)r * 1024 + p * 128 + c4 * 16),
            (__attribute__((address_space(3))) void*)((char*)Wl + o), 16, 0, 0);
    }
}

// W2 slice p into buffer b: [256 rows][8 f4-cols] = 32 KB.
__device__ __forceinline__ void stage_w2(const char* w2e, float* Wl, int b, int p, int tid) {
    #pragma unroll
    for (int j = 0; j < 2; ++j) {
        const int o  = (j * 1024 + tid) * 16;          // byte in 32 KB image
        const int r  = o >> 7;                          // row 0..255
        const int c4 = ((o >> 4) & 7) ^ (r & 7);
        __builtin_amdgcn_global_load_lds(
            (const __attribute__((address_space(1))) void*)(w2e + (size_t)r * 2048 + p * 128 + c4 * 16),
            (__attribute__((address_space(3))) void*)((char*)Wl + b * 32768 + o), 16, 0, 0);
    }
}

__global__ __launch_bounds__(1024, 4) void expert_kernel(
    const float* __restrict__ x,
    const float* __restrict__ w1s, const float* __restrict__ b1s,
    const float* __restrict__ w2s, const float* __restrict__ b2s,
    const int* __restrict__ counts, const int* __restrict__ lists,
    const float* __restrict__ esc, float* __restrict__ out)
{
    __shared__ __align__(16) float Wl[16384];          // 64 KB weight slice / dbuf
    __shared__ __align__(16) float xst[T_CAP * 512];   // 24 KB transposed x
    __shared__ __align__(16) float vsm[T_CAP * 256];   // 12 KB transposed v
    __shared__ int   slotIds[T_CAP];
    __shared__ float escv[T_CAP];

    const int e  = blockIdx.x;
    const int g  = blockIdx.y;
    const int ne = min(counts[e], LIST_CAP);
    const int tid  = threadIdx.x;
    const int wave = tid >> 6, lane = tid & 63;
    const int slot = wave & 7;            // f4-col slot within 32-col slice
    const int tg   = wave >> 3;           // token group (0/1), 6 tokens each
    const int wslot = slot ^ (lane & 7);  // swizzled storage slot (row&7 == lane&7)

    const char* w1e = (const char*)(w1s + (size_t)e * IN_W * BLOCK_H);
    const char* w2e = (const char*)(w2s + (size_t)e * BLOCK_H * OUT_W);
    const float4* b1v = (const float4*)(b1s + (size_t)e * BLOCK_H);
    const float4* b2v = (const float4*)(b2s + (size_t)e * OUT_W);
    const float4* x4  = (const float4*)x;

    for (int s0 = g; s0 < ne; s0 += NGRP * T_CAP) {
        const int nTok = min(T_CAP, (ne - s0 + NGRP - 1) / NGRP);

        if (tid < T_CAP) {
            int s = 0; float sc = 0.f;
            if (tid < nTok) { s = lists[e * LIST_CAP + s0 + tid * NGRP]; sc = esc[s]; }
            slotIds[tid] = s;
            escv[tid]    = sc;
        }
        __syncthreads();

        // issue W1 slice 0 DMA; stage x transposed (zero-pad); one drain for both
        stage_w1(w1e, Wl, 0, tid);
        for (int idx = tid; idx < T_CAP * 128; idx += 1024) {
            const int t = idx >> 7, q = idx & 127;
            float4 v = make_float4(0.f, 0.f, 0.f, 0.f);
            if (t < nTok) v = x4[(size_t)(slotIds[t] >> 1) * 128 + q];
            // x[t][i] -> xst[t*512 + (i>>6 ? ... )]: addr = t*512 + (s>>2)*256 + l*4 + (s&3)
            const int s = q >> 4, qm = q & 15;
            const int base = t * 512 + (s >> 2) * 256 + 16 * qm + (s & 3);
            xst[base +  0] = v.x;
            xst[base +  4] = v.y;
            xst[base +  8] = v.z;
            xst[base + 12] = v.w;
        }
        __syncthreads();

        // ---- phase 1: v = relu(x @ W1 + b1), 8 weight slices ----
        for (int p = 0; p < 8; ++p) {
            float4 acc[6];
            #pragma unroll
            for (int t = 0; t < 6; ++t) acc[t] = make_float4(0.f, 0.f, 0.f, 0.f);
            const float* xb = xst + (tg * 6) * 512 + lane * 4;
            #pragma unroll
            for (int c = 0; c < 2; ++c) {
                float4 xv[6];
                #pragma unroll
                for (int t = 0; t < 6; ++t) xv[t] = *(const float4*)&xb[t * 512 + c * 256];
                #pragma unroll
                for (int s4 = 0; s4 < 4; ++s4) {
                    const float4 w = *(const float4*)&Wl[((c * 4 + s4) * 64 + lane) * 32 + wslot * 4];
                    #pragma unroll
                    for (int t = 0; t < 6; ++t) fma4(acc[t], comp(xv[t], s4), w);
                }
            }
            #pragma unroll
            for (int t = 0; t < 6; ++t) {
                red_xor(acc[t], 1); red_xor(acc[t], 2); red_xor(acc[t], 4);
                red_xor(acc[t], 8); red_xor(acc[t], 16); red_xor(acc[t], 32);
            }
            {
                const float4 bb = b1v[p * 8 + slot];
                const int k = lane & 3;
                #pragma unroll
                for (int tt = 0; tt < 6; ++tt) {
                    if ((lane >> 3) == tt && (lane & 4) == 0) {   // acc[tt] static-indexed
                        float av = fmaxf(comp(acc[tt], k) + comp(bb, k), 0.f);
                        const int h = p * 32 + slot * 4 + k;
                        vsm[(tg * 6 + tt) * 256 + (h & 63) * 4 + (h >> 6)] = av;
                    }
                }
            }
            __syncthreads();                       // all reads of Wl done
            if (p + 1 < 8) stage_w1(w1e, Wl, p + 1, tid);
            else           stage_w2(w2e, Wl, 0, 0, tid);
            __syncthreads();                       // DMA drained (next data ready)
        }

        // ---- phase 2: out += sc*(v @ W2 + b2), 16 slices, double-buffered ----
        for (int p = 0; p < 16; ++p) {
            if (p + 1 < 16) stage_w2(w2e, Wl, (p + 1) & 1, p + 1, tid);  // flies under compute
            const float* Wb = Wl + (p & 1) * 8192;
            float4 acc[6];
            #pragma unroll
            for (int t = 0; t < 6; ++t) acc[t] = make_float4(0.f, 0.f, 0.f, 0.f);
            float4 vv[6];
            #pragma unroll
            for (int t = 0; t < 6; ++t) vv[t] = *(const float4*)&vsm[(tg * 6 + t) * 256 + lane * 4];
            #pragma unroll
            for (int s2 = 0; s2 < 4; ++s2) {
                const float4 w = *(const float4*)&Wb[(s2 * 64 + lane) * 32 + wslot * 4];
                #pragma unroll
                for (int t = 0; t < 6; ++t) fma4(acc[t], comp(vv[t], s2), w);
            }
            #pragma unroll
            for (int t = 0; t < 6; ++t) {
                red_xor(acc[t], 1); red_xor(acc[t], 2); red_xor(acc[t], 4);
                red_xor(acc[t], 8); red_xor(acc[t], 16); red_xor(acc[t], 32);
            }
            {
                const float4 bb = b2v[p * 8 + slot];
                const int k = lane & 3;
                #pragma unroll
                for (int tt = 0; tt < 6; ++tt) {
                    const int t = tg * 6 + tt;
                    if ((lane >> 3) == tt && (lane & 4) == 0 && t < nTok) {
                        const int col = p * 32 + slot * 4 + k;
                        atomicAdd(out + (size_t)(slotIds[t] >> 1) * OUT_W + col,
                                  (comp(acc[tt], k) + comp(bb, k)) * escv[t]);
                    }
                }
            }
            __syncthreads();   // drains next-slice DMA; frees buf (p&1) for p+2
        }
        __syncthreads();       // xst/vsm/meta reused next pass (rare: ne > 48)
    }
}

extern "C" void kernel_launch(void* const* d_in, const int* in_sizes, int n_in,
                              void* d_out, int out_size, void* d_ws, size_t ws_size,
                              hipStream_t stream) {
    const float* x      = (const float*)d_in[0];
    const float* noise  = (const float*)d_in[1];
    const float* w1s    = (const float*)d_in[2];
    const float* b1s    = (const float*)d_in[3];
    const float* w2s    = (const float*)d_in[4];
    const float* b2s    = (const float*)d_in[5];
    const float* mixer  = (const float*)d_in[6];
    const float* noisec = (const float*)d_in[7];
    float* out = (float*)d_out;

    // workspace: ~41 KB total (keep FAR under ws_size)
    char* ws = (char*)d_ws;
    int*   counts = (int*)ws;                       ws += 256;
    float* esc    = (float*)ws;                     ws += NSLOTS * sizeof(float);
    int*   lists  = (int*)ws;   /* 64 * 128 ints = 32 KB */

    hipMemsetAsync(counts, 0, 256, stream);

    routing_kernel<<<TOKENS / 2, 256, 0, stream>>>(x, noise, mixer, noisec,
                                                   esc, counts, lists, out);
    expert_kernel<<<dim3(N_EXPERTS, NGRP), 1024, 0, stream>>>(
        x, w1s, b1s, w2s, b2s, counts, lists, esc, out);
}

// Round 7
// 168.787 us; speedup vs baseline: 2.0284x; 2.0284x over previous
//
#include <hip/hip_runtime.h>
#include <math.h>

#define TOKENS    1024
#define IN_W      512
#define BLOCK_H   256
#define OUT_W     512
#define N_EXPERTS 64
#define TOPK      2
#define NSLOTS    (TOKENS * TOPK)
#define LIST_CAP  128     // ne ~ Binom(2048,1/64): mean 32, sigma 5.6; 128 is +17 sigma
#define T_CAP     12      // tokens per pass; ne <= 48 in one pass (99.8%)
#define NGRP      4       // groups per expert -> grid 256 = 1 block/CU
#define XPAD      520     // x row stride (floats); 2080 B, 16B-aligned
#define VPAD      264     // v row stride; 1056 B, 16B-aligned

__device__ __forceinline__ void red_xor(float4& v, int m) {
    v.x += __shfl_xor(v.x, m); v.y += __shfl_xor(v.y, m);
    v.z += __shfl_xor(v.z, m); v.w += __shfl_xor(v.w, m);
}

__device__ __forceinline__ void fma4(float4& a, float s, const float4& w) {
    a.x = fmaf(s, w.x, a.x); a.y = fmaf(s, w.y, a.y);
    a.z = fmaf(s, w.z, a.z); a.w = fmaf(s, w.w, a.w);
}

// ---------------------------------------------------------------------------
// Routing v2: 1 token/block x 1024 blocks (4096 waves = 16/CU, 2x occupancy
// vs v1) ; wave = i-quarter -> critical path 256 -> 32 iterations; float4
// loads cover 4 rows x 64 experts = 1 KB/wave-instr (4x fewer load instrs).
// Also zeroes this token's out row (folds the 2 MB memset dispatch).
// ---------------------------------------------------------------------------
__global__ __launch_bounds__(256) void routing_kernel(
    const float* __restrict__ x, const float* __restrict__ noise,
    const float* __restrict__ mixer, const float* __restrict__ noisec,
    float* __restrict__ esc, int* __restrict__ counts, int* __restrict__ lists,
    float* __restrict__ out)
{
    __shared__ float xs[512];
    __shared__ float pm[4 * 64];   // [quarter][expert] mixer partials
    __shared__ float pn[4 * 64];
    __shared__ float hs[64];
    const int t    = blockIdx.x;          // token
    const int tid  = threadIdx.x;
    const int wave = tid >> 6, lane = tid & 63;   // wave = i-quarter 0..3
    const int rs   = lane >> 4;           // row-sub 0..3
    const int c    = lane & 15;           // f4 expert-col (4 experts)

    if (tid < 128) {
        ((float4*)xs)[tid] = ((const float4*)(x + (size_t)t * IN_W))[tid];
        ((float4*)(out + (size_t)t * OUT_W))[tid] = make_float4(0.f, 0.f, 0.f, 0.f);
    }
    __syncthreads();

    // quarter rows [wave*128, wave*128+128); per j: rows j*4+rs (4 rows/wave)
    float4 am = make_float4(0.f, 0.f, 0.f, 0.f), an = am;
    const float4* m4 = (const float4*)mixer;
    const float4* n4 = (const float4*)noisec;
    const int rbase = wave * 128;
    #pragma unroll 4
    for (int j = 0; j < 32; ++j) {
        const int r = rbase + j * 4 + rs;
        const float xv = xs[r];                   // 4 addrs/wave, 16-lane broadcast
        const float4 wm = m4[r * 16 + c];         // wave: 4 rows x 256 B = 1 KB
        const float4 wn = n4[r * 16 + c];
        fma4(am, xv, wm);
        fma4(an, xv, wn);
    }
    red_xor(am, 16); red_xor(am, 32);             // sum over rs groups
    red_xor(an, 16); red_xor(an, 32);
    if (lane < 16) {
        *(float4*)&pm[wave * 64 + lane * 4] = am; // experts lane*4..+3
        *(float4*)&pn[wave * 64 + lane * 4] = an;
    }
    __syncthreads();

    if (tid < 64) {   // final reduce over quarters + noisy logit
        const float am2 = pm[tid] + pm[64 + tid] + pm[128 + tid] + pm[192 + tid];
        const float an2 = pn[tid] + pn[64 + tid] + pn[128 + tid] + pn[192 + tid];
        // softplus(v) = max(v,0) + log1p(exp(-|v|))
        const float sp = fmaxf(an2, 0.f) + log1pf(expf(-fabsf(an2)));
        hs[tid] = am2 + noise[(size_t)t * 64 + tid] * sp;
    }
    __syncthreads();

    if (tid == 0) {
        float b0 = -INFINITY, b1 = -INFINITY;
        int i0 = 0, i1 = 0;
        for (int i = 0; i < N_EXPERTS; ++i) {
            const float v = hs[i];
            if (v > b0)      { b1 = b0; i1 = i0; b0 = v; i0 = i; }  // strict >: stable ties
            else if (v > b1) { b1 = v; i1 = i; }
        }
        const float z   = expf(b1 - b0);
        const float inv = 1.f / (1.f + z);
        esc[t * 2 + 0] = inv;
        esc[t * 2 + 1] = z * inv;
        const int p0 = atomicAdd(&counts[i0], 1);
        if (p0 < LIST_CAP) lists[i0 * LIST_CAP + p0] = t * 2 + 0;
        const int p1 = atomicAdd(&counts[i1], 1);
        if (p1 < LIST_CAP) lists[i1 * LIST_CAP + p1] = t * 2 + 1;
    }
}

// ---------------------------------------------------------------------------
// Fused expert FFN: VERBATIM round-1 kernel (verified 53 us; best of 6
// rounds). Rounds 2-6 showed every restructure loses: register prefetch ->
// spill (r2), wider unroll -> scheduler bursts (r3), 2 blocks/CU -> VGPR 32
// spill (r4), global_load_lds chunks -> serial drains + conflicts (r5),
// weight-stationary -> inherent b128 8-phase + barrier overhead (r6).
// ---------------------------------------------------------------------------
template<int T>
__device__ __forceinline__ void run_pass(
    int nTok, int wave, int lane,
    const float4* __restrict__ w1v, const float4* __restrict__ w2v,
    const float4* __restrict__ b1v, const float4* __restrict__ b2v,
    const float* __restrict__ xs, float* __restrict__ vsm,
    const int* __restrict__ slotIds, const float* __restrict__ escv,
    float* __restrict__ out)
{
    // ---- phase 1: v = relu(x @ W1 + b1) ----
    // wave covers cols [wave*16, wave*16+16); lane = (r0 = lane>>2, c4l = lane&3)
    // row = s*16 + r0; per instr: 16 row-chunks x 64 B = 1 KB unique weights.
    {
        const int c4l = lane & 3, r0 = lane >> 2;
        float4 acc[T];
        #pragma unroll
        for (int t = 0; t < T; ++t) acc[t] = make_float4(0.f, 0.f, 0.f, 0.f);
        const float4* wp = w1v + (size_t)(r0 * 64 + wave * 4 + c4l);
        const float*  xb = xs + r0;
        #pragma unroll 2
        for (int s = 0; s < 32; ++s) {
            const float4 w = wp[(size_t)s * 1024];   // rows s*16+r0, col f4 wave*4+c4l
            #pragma unroll
            for (int t = 0; t < T; ++t) {
                const float xv = xb[t * XPAD + s * 16];   // 16 banks, 4-lane broadcast
                acc[t].x = fmaf(xv, w.x, acc[t].x);
                acc[t].y = fmaf(xv, w.y, acc[t].y);
                acc[t].z = fmaf(xv, w.z, acc[t].z);
                acc[t].w = fmaf(xv, w.w, acc[t].w);
            }
        }
        #pragma unroll
        for (int t = 0; t < T; ++t) {      // reduce over r0 (lane bits 2..5)
            red_xor(acc[t], 4); red_xor(acc[t], 8);
            red_xor(acc[t], 16); red_xor(acc[t], 32);
        }
        if (r0 == 0) {
            const float4 bb = b1v[wave * 4 + c4l];
            #pragma unroll
            for (int t = 0; t < T; ++t) {
                float4 r;
                r.x = fmaxf(acc[t].x + bb.x, 0.f);
                r.y = fmaxf(acc[t].y + bb.y, 0.f);
                r.z = fmaxf(acc[t].z + bb.z, 0.f);
                r.w = fmaxf(acc[t].w + bb.w, 0.f);
                *(float4*)&vsm[t * VPAD + wave * 16 + c4l * 4] = r;
            }
        }
    }
    __syncthreads();

    // ---- phase 2: out += sc * (v @ W2 + b2), straight to global atomics ----
    // wave covers cols [wave*32, wave*32+32); lane = (r8 = lane>>3, c8 = lane&7)
    // row = s*8 + r8; per instr: 8 row-chunks x 128 B contiguous.
    {
        const int c8 = lane & 7, r8 = lane >> 3;
        float4 acc[T];
        #pragma unroll
        for (int t = 0; t < T; ++t) acc[t] = make_float4(0.f, 0.f, 0.f, 0.f);
        const float4* wp = w2v + (size_t)(r8 * 128 + wave * 8 + c8);
        const float*  vb = vsm + r8;
        #pragma unroll 2
        for (int s = 0; s < 32; ++s) {
            const float4 w = wp[(size_t)s * 1024];   // rows s*8+r8, col f4 wave*8+c8
            #pragma unroll
            for (int t = 0; t < T; ++t) {
                const float vv = vb[t * VPAD + s * 8];    // 8 banks, 8-lane broadcast
                acc[t].x = fmaf(vv, w.x, acc[t].x);
                acc[t].y = fmaf(vv, w.y, acc[t].y);
                acc[t].z = fmaf(vv, w.z, acc[t].z);
                acc[t].w = fmaf(vv, w.w, acc[t].w);
            }
        }
        #pragma unroll
        for (int t = 0; t < T; ++t) {      // reduce over r8 (lane bits 3..5)
            red_xor(acc[t], 8); red_xor(acc[t], 16); red_xor(acc[t], 32);
        }
        // butterfly leaves the full sum in every lane; spread the token loop
        // across r8 groups so all 64 lanes issue atomics (static t indexing).
        const float4 bb = b2v[wave * 8 + c8];
        #pragma unroll
        for (int t = 0; t < T; ++t) {
            if ((t & 7) == r8 && t < nTok) {
                const float sc = escv[t];
                float* o = out + (size_t)(slotIds[t] >> 1) * OUT_W
                               + (wave * 8 + c8) * 4;
                atomicAdd(o + 0, (acc[t].x + bb.x) * sc);
                atomicAdd(o + 1, (acc[t].y + bb.y) * sc);
                atomicAdd(o + 2, (acc[t].z + bb.z) * sc);
                atomicAdd(o + 3, (acc[t].w + bb.w) * sc);
            }
        }
    }
}

__global__ __launch_bounds__(1024, 4) void expert_kernel(
    const float* __restrict__ x,
    const float* __restrict__ w1s, const float* __restrict__ b1s,
    const float* __restrict__ w2s, const float* __restrict__ b2s,
    const int* __restrict__ counts, const int* __restrict__ lists,
    const float* __restrict__ esc, float* __restrict__ out)
{
    __shared__ __align__(16) float xs[T_CAP * XPAD];   // ~25.0 KB
    __shared__ __align__(16) float vsm[T_CAP * VPAD];  // ~12.7 KB
    __shared__ int   slotIds[T_CAP];
    __shared__ float escv[T_CAP];

    const int e  = blockIdx.x;
    const int g  = blockIdx.y;
    const int ne = min(counts[e], LIST_CAP);
    const int tid  = threadIdx.x;
    const int wave = tid >> 6, lane = tid & 63;

    const float4* w1v = (const float4*)(w1s + (size_t)e * IN_W * BLOCK_H);
    const float4* w2v = (const float4*)(w2s + (size_t)e * BLOCK_H * OUT_W);
    const float4* b1v = (const float4*)(b1s + (size_t)e * BLOCK_H);
    const float4* b2v = (const float4*)(b2s + (size_t)e * OUT_W);
    const float4* x4  = (const float4*)x;

    // pass p handles slot indices j = s0 + i*NGRP, i < T_CAP, s0 = g + p*48
    for (int s0 = g; s0 < ne; s0 += NGRP * T_CAP) {
        const int nTok  = min(T_CAP, (ne - s0 + NGRP - 1) / NGRP);
        const int Tpath = (nTok <= 4) ? 4 : (nTok <= 8) ? 8 : 12;

        if (tid < T_CAP) {
            int s = 0; float sc = 0.f;
            if (tid < nTok) { s = lists[e * LIST_CAP + s0 + tid * NGRP]; sc = esc[s]; }
            slotIds[tid] = s;
            escv[tid]    = sc;
        }
        __syncthreads();

        // stage Tpath token rows (zero-pad missing)
        for (int idx = tid; idx < Tpath * 128; idx += 1024) {
            const int t = idx >> 7, q = idx & 127;
            float4 v = make_float4(0.f, 0.f, 0.f, 0.f);
            if (t < nTok) v = x4[(size_t)(slotIds[t] >> 1) * 128 + q];
            *(float4*)&xs[t * XPAD + q * 4] = v;
        }
        __syncthreads();

        if (nTok <= 4)
            run_pass<4>(nTok, wave, lane, w1v, w2v, b1v, b2v, xs, vsm, slotIds, escv, out);
        else if (nTok <= 8)
            run_pass<8>(nTok, wave, lane, w1v, w2v, b1v, b2v, xs, vsm, slotIds, escv, out);
        else
            run_pass<12>(nTok, wave, lane, w1v, w2v, b1v, b2v, xs, vsm, slotIds, escv, out);
        __syncthreads();   // xs/vsm reused next pass (rare: ne > 48)
    }
}

extern "C" void kernel_launch(void* const* d_in, const int* in_sizes, int n_in,
                              void* d_out, int out_size, void* d_ws, size_t ws_size,
                              hipStream_t stream) {
    const float* x      = (const float*)d_in[0];
    const float* noise  = (const float*)d_in[1];
    const float* w1s    = (const float*)d_in[2];
    const float* b1s    = (const float*)d_in[3];
    const float* w2s    = (const float*)d_in[4];
    const float* b2s    = (const float*)d_in[5];
    const float* mixer  = (const float*)d_in[6];
    const float* noisec = (const float*)d_in[7];
    float* out = (float*)d_out;

    // workspace: ~41 KB total (keep FAR under ws_size)
    char* ws = (char*)d_ws;
    int*   counts = (int*)ws;                       ws += 256;
    float* esc    = (float*)ws;                     ws += NSLOTS * sizeof(float);
    int*   lists  = (int*)ws;   /* 64 * 128 ints = 32 KB */

    hipMemsetAsync(counts, 0, 256, stream);

    routing_kernel<<<TOKENS, 256, 0, stream>>>(x, noise, mixer, noisec,
                                               esc, counts, lists, out);
    expert_kernel<<<dim3(N_EXPERTS, NGRP), 1024, 0, stream>>>(
        x, w1s, b1s, w2s, b2s, counts, lists, esc, out);
}